// Round 3
// baseline (209.707 us; speedup 1.0000x reference)
//
#include <hip/hip_runtime.h>

// MLP depends only on X[b] (1000 distinct values) -> params table, gathered
// by the scan. R15: merge scan_a+scan_b into ONE kernel (scan_one). The
// a/b split ran the 200-step chain TWICE (scan_a checkpoint + scan_b replay)
// plus an 8MB cpA/maskA round-trip plus a dispatch boundary — but the only
// thing the split bought (coalesced stores via LDS tile) doesn't need the
// replay: one kernel chains 32 rows (lane=row, scan_a's verified full-lane
// pattern), emits latents into scan_b's verified 32x200 LDS tile, then does
// scan_b's verified contiguous sweep. Bit-exact sequence -> absmax
// unchanged. Width preserved: 2048 blocks (R11/R13 lesson: never narrow).
// Kept lessons: R5 strided stores = 4.85x write amp -> LDS tile + contiguous
// stores; R7 grid.sync ~60us/barrier; R8 per-load dtype branch = latency
// death; R11/R13 fusion kills width; R14 scan_b occupancy was NOT the limit.

typedef unsigned int uint;
typedef unsigned char uchar;
typedef unsigned short ushort_t;
typedef __attribute__((ext_vector_type(8))) short short8;
typedef __attribute__((ext_vector_type(4))) float f32x4;
typedef __attribute__((ext_vector_type(2))) uint uint2v;

#define SS 1000
#define HH 512
#define TT 200
#define BB_ 65536
#define PP 5

#define OFF_EMB   0
#define OFF_B1    512000
#define OFF_B2    512512
#define OFF_WOUT  513024
#define OFF_BOUT  515584
#define CONV_TOT  515589

__device__ __forceinline__ float b2f(ushort_t u) {
    return __uint_as_float(((uint)u) << 16);
}
__device__ __forceinline__ ushort_t f2b(float f) {
    uint u = __float_as_uint(f);
    uint r = u + 0x7FFFu + ((u >> 16) & 1u);   // RNE
    return (ushort_t)(r >> 16);
}
// Per-wave dtype detect (R2-R14: dataset is f32; keep both paths).
__device__ __forceinline__ int detect_bf16(const uint* __restrict__ embed_raw,
                                           int tid) {
    uint w = embed_raw[tid & 63];
    uint e = (w >> 7) & 0xFFu;
    bool pl = (e >= 117u && e <= 130u);
    return __popcll(__ballot(pl)) >= 32 ? 1 : 0;
}
__device__ __forceinline__ ushort_t ld_bf16(const void* src, int idx, int fb) {
    return fb ? ((const ushort_t*)src)[idx] : f2b(((const float*)src)[idx]);
}

// The one true scan step (identical fp ops/order everywhere -> trajectories
// are bit-exact regardless of which kernel runs them).
__device__ __forceinline__ float bkt_step(float latent, bool yt,
                                          float oms, float omg, float A1,
                                          float A0, float g, float s,
                                          float oml, float l) {
    float num1    = latent * oms;
    float correct = fmaf(latent, A1, g);
    float lats    = latent * s;
    float num = yt ? num1 : lats;
    float den = yt ? correct : fmaf(latent, A0, omg);
    float kt  = num * __builtin_amdgcn_rcpf(den);
    float nxt = fmaf(kt, oml, l);
    return fminf(fmaxf(nxt, 1e-6f), 1.f - 1e-6f);
}

// ------------------------------------------------------------------- prep
// [0,504): vectorized conv copy. [504,1016): 32x32 transpose tiles W1/W2.
__global__ __launch_bounds__(256) void prep_kernel(
    const void* __restrict__ embed, const void* __restrict__ W1,
    const void* __restrict__ b1,    const void* __restrict__ W2,
    const void* __restrict__ b2,    const void* __restrict__ Wout,
    const void* __restrict__ bout,
    ushort_t* __restrict__ conv, ushort_t* __restrict__ WT1,
    ushort_t* __restrict__ WT2)
{
    int tid = threadIdx.x;
    int fb = detect_bf16((const uint*)embed, tid);
    int bx = blockIdx.x;
    if (bx < 504) {
        int i = (bx * 256 + tid) * 4;
        if (i < CONV_TOT) {
            const void* src; int off;
            if      (i < OFF_B1)   { src = embed; off = i; }
            else if (i < OFF_B2)   { src = b1;    off = i - OFF_B1; }
            else if (i < OFF_WOUT) { src = b2;    off = i - OFF_B2; }
            else if (i < OFF_BOUT) { src = Wout;  off = i - OFF_WOUT; }
            else                   { src = bout;  off = i - OFF_BOUT; }
            if (i + 3 < CONV_TOT) {
                ushort4 o;
                if (fb) {
                    o = *(const ushort4*)((const ushort_t*)src + off);
                } else {
                    float4 v = *(const float4*)((const float*)src + off);
                    o.x = f2b(v.x); o.y = f2b(v.y); o.z = f2b(v.z); o.w = f2b(v.w);
                }
                *(ushort4*)(conv + i) = o;
            } else {
                for (int k = 0; i + k < CONV_TOT; k++)
                    conv[i + k] = ld_bf16(src, off + k, fb);
            }
        }
    } else {
        __shared__ ushort_t t[32][33];
        int bi = bx - 504;
        const void* W = bi < 256 ? W1 : W2;
        ushort_t* WT = bi < 256 ? WT1 : WT2;
        int ti = bi & 255;
        int k0 = (ti & 15) * 32, n0 = (ti >> 4) * 32;
        int tx = tid & 31, ty = tid >> 5;
        #pragma unroll
        for (int i = ty; i < 32; i += 8)
            t[i][tx] = ld_bf16(W, (k0 + i) * HH + n0 + tx, fb);
        __syncthreads();
        #pragma unroll
        for (int i = ty; i < 32; i += 8)
            WT[(n0 + i) * HH + k0 + tx] = t[tx][i];
    }
}

// -------------------------------------------------------------- MLP layer
// Wave computes a 16x16 MFMA tile; grid (16,32)=512 blocks (2/CU).
__global__ __launch_bounds__(256) void mlp_layer(
    const ushort_t* __restrict__ A, const ushort_t* __restrict__ WT,
    const ushort_t* __restrict__ bias, ushort_t* __restrict__ H, int Mclamp)
{
    int tid = threadIdx.x;
    int lane = tid & 63;
    int wave = tid >> 6;
    int m_base = blockIdx.x * 64 + wave * 16;
    int n_base = blockIdx.y * 16;
    int lrow = lane & 15;
    int q = lane >> 4;
    int rowA = m_base + lrow; if (rowA > Mclamp) rowA = Mclamp;

    const short8* Ap = (const short8*)(A + (size_t)rowA * HH) + q;
    const short8* Bp = (const short8*)(WT + (size_t)(n_base + lrow) * HH) + q;

    f32x4 acc = {0.f, 0.f, 0.f, 0.f};
    #pragma unroll 8
    for (int kk = 0; kk < 16; kk++) {
        short8 a = Ap[kk * 4];
        short8 b = Bp[kk * 4];
        acc = __builtin_amdgcn_mfma_f32_16x16x32_bf16(a, b, acc, 0, 0, 0);
    }

    int orow = m_base + q * 4;                 // C/D: col=lane&15, row=q*4+reg
    int n = n_base + lrow;
    float bb = b2f(bias[n]);
    #pragma unroll
    for (int r = 0; r < 4; r++) {
        float v = acc[r] + bb;
        H[(size_t)(orow + r) * HH + n] = f2b(fmaxf(v, 0.f));
    }
}

// ---------------------------------------------------------------- params
__global__ __launch_bounds__(256) void params_kernel(
    const ushort_t* __restrict__ h2, const ushort_t* __restrict__ conv,
    float* __restrict__ table)
{
    int wid = blockIdx.x * 4 + (threadIdx.x >> 6);
    int lane = threadIdx.x & 63;
    if (wid >= SS * PP) return;
    int row = wid / PP, p = wid - row * PP;
    const ushort_t* Wout = conv + OFF_WOUT;
    const ushort_t* bout = conv + OFF_BOUT;
    const short8* hr = (const short8*)(h2 + (size_t)row * HH);
    short8 h = hr[lane];
    float acc = 0.f;
    #pragma unroll
    for (int j = 0; j < 8; j++) {
        int k = lane * 8 + j;
        acc += b2f((ushort_t)h[j]) * b2f(Wout[k * PP + p]);
    }
    #pragma unroll
    for (int m = 32; m; m >>= 1) acc += __shfl_xor(acc, m);
    if (lane == 0) {
        float x = acc + b2f(bout[p]);
        float sg = 1.f / (1.f + expf(-x));
        sg = fminf(fmaxf(sg, 1e-6f), 1.f - 1e-6f);
        table[(size_t)row * 8 + p] = sg;
    }
}

// --------------------------------------------------------------- scan_one
// R15: single-pass scan. 2048 blocks x 128, 32 rows/block, lane=row.
// Phase 1: stage y -> LDS nibbles (coalesced int4, all 128 threads).
// Phase 2: lanes 0-31 of wave 0 chain their row 200 exact steps (identical
//   sequence to old scan_a), emitting latent_t into the 32x200 LDS tile
//   (ds_write hidden under the ~30cyc dependent step chain); params plane
//   written per-lane up front.
// Phase 3: scan_b's verified sweep — corrects = fma(lat,A1,g), both planes
//   streamed as contiguous 16B stores.
// LDS 27.4KB -> 5 blocks/CU; chain halves overlap with neighbors' phases.
__global__ __launch_bounds__(128) void scan_one(
    const int* __restrict__ X, const int* __restrict__ y,
    const float* __restrict__ table, const uint* __restrict__ embed_raw,
    void* __restrict__ out)
{
    __shared__ __align__(16) float stg[32 * 200];      // 25600 B
    __shared__ uchar ybit[32 * 50];                    // 1600 B
    __shared__ float pA1[32], pG[32];
    int tid = threadIdx.x;
    int rbase = blockIdx.x * 32;
    int fb = detect_bf16(embed_raw, tid);

    for (int idx = tid; idx < 1600; idx += 128) {
        int r = idx / 50, k = idx - r * 50;
        int4 v = *(const int4*)(y + (size_t)(rbase + r) * TT + k * 4);
        ybit[r * 50 + k] = (uchar)((uint)(v.x == 1) | ((uint)(v.y == 1) << 1) |
                                   ((uint)(v.z == 1) << 2) | ((uint)(v.w == 1) << 3));
    }
    __syncthreads();

    if (tid < 32) {
        int rg = rbase + tid;
        int xi = X[rg]; xi = xi < 0 ? 0 : (xi >= SS ? SS - 1 : xi);
        float l      = table[xi * 8 + 0];
        float p1     = table[xi * 8 + 1];
        float g      = table[xi * 8 + 2];
        float s      = table[xi * 8 + 3];
        float latent = table[xi * 8 + 4];
        pA1[tid] = 1.f - s - g;
        pG[tid]  = g;

        size_t po = 2ull * BB_ * TT + (size_t)rg * 5;
        if (fb) {
            ushort_t* op = (ushort_t*)out + po;
            op[0] = f2b(l); op[1] = f2b(p1); op[2] = f2b(g);
            op[3] = f2b(s); op[4] = f2b(latent);
        } else {
            float* op = (float*)out + po;
            op[0] = l; op[1] = p1; op[2] = g; op[3] = s; op[4] = latent;
        }

        float oms = 1.f - s, omg = 1.f - g, oml = 1.f - l;
        float A1 = 1.f - s - g, A0 = s + g - 1.f;
        const uchar* yb = &ybit[tid * 50];
        float* sp = &stg[tid * 200];
        #pragma unroll 4
        for (int t = 0; t < 200; t++) {
            sp[t] = latent;
            uint bit = (yb[t >> 2] >> (t & 3)) & 1u;
            latent = bkt_step(latent, bit, oms, omg, A1, A0, g, s, oml, l);
        }
    }
    __syncthreads();

    const f32x4* src = (const f32x4*)stg;
    if (!fb) {
        f32x4* dc = (f32x4*)((float*)out + (size_t)rbase * TT);
        f32x4* dl = (f32x4*)((float*)out + (size_t)BB_ * TT + (size_t)rbase * TT);
        for (int idx = tid; idx < 1600; idx += 128) {
            int rr = idx / 50;
            f32x4 v = src[idx];
            float a1 = pA1[rr], gg = pG[rr];
            f32x4 c;
            c[0] = fmaf(v[0], a1, gg); c[1] = fmaf(v[1], a1, gg);
            c[2] = fmaf(v[2], a1, gg); c[3] = fmaf(v[3], a1, gg);
            dl[idx] = v;
            dc[idx] = c;
        }
    } else {
        uint2v* dc = (uint2v*)((ushort_t*)out + (size_t)rbase * TT);
        uint2v* dl = (uint2v*)((ushort_t*)out + (size_t)BB_ * TT + (size_t)rbase * TT);
        for (int idx = tid; idx < 1600; idx += 128) {
            int rr = idx / 50;
            f32x4 v = src[idx];
            float a1 = pA1[rr], gg = pG[rr];
            uint2v lv, cv;
            lv[0] = (uint)f2b(v[0]) | ((uint)f2b(v[1]) << 16);
            lv[1] = (uint)f2b(v[2]) | ((uint)f2b(v[3]) << 16);
            cv[0] = (uint)f2b(fmaf(v[0], a1, gg)) | ((uint)f2b(fmaf(v[1], a1, gg)) << 16);
            cv[1] = (uint)f2b(fmaf(v[2], a1, gg)) | ((uint)f2b(fmaf(v[3], a1, gg)) << 16);
            dl[idx] = lv;
            dc[idx] = cv;
        }
    }
}

// ---------------------------------------------------------------- launch
extern "C" void kernel_launch(void* const* d_in, const int* in_sizes, int n_in,
                              void* d_out, int out_size, void* d_ws, size_t ws_size,
                              hipStream_t stream) {
    const int* X = (const int*)d_in[0];
    const int* y = (const int*)d_in[1];

    char* ws = (char*)d_ws;
    ushort_t* conv  = (ushort_t*)(ws);                 // ~1.03 MB
    ushort_t* WT1   = (ushort_t*)(ws + 1048576);       // 512 KB
    ushort_t* WT2   = (ushort_t*)(ws + 1572864);       // 512 KB
    ushort_t* h1    = (ushort_t*)(ws + 2097152);       // 1 MB
    ushort_t* h2    = (ushort_t*)(ws + 3145728);       // 1 MB
    float*    table = (float*)(ws + 4194304);          // 32 KB

    prep_kernel<<<dim3(1016, 1, 1), 256, 0, stream>>>(
        d_in[2], d_in[3], d_in[4], d_in[5], d_in[6], d_in[7], d_in[8],
        conv, WT1, WT2);
    mlp_layer<<<dim3(16, 32, 1), 256, 0, stream>>>(
        conv + OFF_EMB, WT1, conv + OFF_B1, h1, SS - 1);
    mlp_layer<<<dim3(16, 32, 1), 256, 0, stream>>>(
        h1, WT2, conv + OFF_B2, h2, 1023);
    params_kernel<<<dim3(1250, 1, 1), 256, 0, stream>>>(h2, conv, table);
    scan_one<<<dim3(2048, 1, 1), 128, 0, stream>>>(
        X, y, table, (const uint*)d_in[2], (void*)d_out);
}

// Round 4
// 205.605 us; speedup vs baseline: 1.0200x; 1.0200x over previous
//
#include <hip/hip_runtime.h>

// MLP depends only on X[b] (1000 distinct values) -> params table, gathered
// by the scan. R16: REVERT to the best-known R12 structure (203.4us).
// Session evidence log:
//   R13 fuse mlp1+mlp2+params (63 blocks): +27.6us — narrow grid kills it.
//   R14 scan_b 4->12 blocks/CU: +2.3us — scan_b NOT occupancy-limited.
//   R15 single-pass scan (half the chain compute, -8MB traffic, -1 launch):
//        +6.3us vs best — scan is at its MEMORY floor (52MB y + 106MB out);
//        the a/b split's replay is free (hidden), and 512-wide scan_a blocks
//        hide the 200-step serial chain better than 2048x32-row blocks.
// Conclusion: every structural lever (fusion, occupancy, replay removal)
// is neutral-or-worse; remaining time = compulsory traffic + fixed harness
// fills (62us each at 84-86% HBM peak in the timed loop) + small-launch
// latency. This file is the roofline candidate.
// Kept lessons: R5 strided stores = 4.85x write amp -> LDS tile + contiguous
// stores; R7 grid.sync ~60us/barrier; R8 per-load dtype branch = latency
// death; NT stores dropped (suspect in low store BW).

typedef unsigned int uint;
typedef unsigned char uchar;
typedef unsigned short ushort_t;
typedef __attribute__((ext_vector_type(8))) short short8;
typedef __attribute__((ext_vector_type(4))) float f32x4;
typedef __attribute__((ext_vector_type(2))) uint uint2v;

#define SS 1000
#define HH 512
#define TT 200
#define BB_ 65536
#define PP 5

#define OFF_EMB   0
#define OFF_B1    512000
#define OFF_B2    512512
#define OFF_WOUT  513024
#define OFF_BOUT  515584
#define CONV_TOT  515589

__device__ __forceinline__ float b2f(ushort_t u) {
    return __uint_as_float(((uint)u) << 16);
}
__device__ __forceinline__ ushort_t f2b(float f) {
    uint u = __float_as_uint(f);
    uint r = u + 0x7FFFu + ((u >> 16) & 1u);   // RNE
    return (ushort_t)(r >> 16);
}
// Per-wave dtype detect (R2-R15: dataset is f32; keep both paths).
__device__ __forceinline__ int detect_bf16(const uint* __restrict__ embed_raw,
                                           int tid) {
    uint w = embed_raw[tid & 63];
    uint e = (w >> 7) & 0xFFu;
    bool pl = (e >= 117u && e <= 130u);
    return __popcll(__ballot(pl)) >= 32 ? 1 : 0;
}
__device__ __forceinline__ ushort_t ld_bf16(const void* src, int idx, int fb) {
    return fb ? ((const ushort_t*)src)[idx] : f2b(((const float*)src)[idx]);
}

// The one true scan step (same fp ops/order in scan_a and scan_b so
// checkpoint-resumed trajectories are bit-exact).
__device__ __forceinline__ float bkt_step(float latent, bool yt,
                                          float oms, float omg, float A1,
                                          float A0, float g, float s,
                                          float oml, float l) {
    float num1    = latent * oms;
    float correct = fmaf(latent, A1, g);
    float lats    = latent * s;
    float num = yt ? num1 : lats;
    float den = yt ? correct : fmaf(latent, A0, omg);
    float kt  = num * __builtin_amdgcn_rcpf(den);
    float nxt = fmaf(kt, oml, l);
    return fminf(fmaxf(nxt, 1e-6f), 1.f - 1e-6f);
}

// ------------------------------------------------------------------- prep
// [0,504): vectorized conv copy. [504,1016): 32x32 transpose tiles W1/W2.
__global__ __launch_bounds__(256) void prep_kernel(
    const void* __restrict__ embed, const void* __restrict__ W1,
    const void* __restrict__ b1,    const void* __restrict__ W2,
    const void* __restrict__ b2,    const void* __restrict__ Wout,
    const void* __restrict__ bout,
    ushort_t* __restrict__ conv, ushort_t* __restrict__ WT1,
    ushort_t* __restrict__ WT2)
{
    int tid = threadIdx.x;
    int fb = detect_bf16((const uint*)embed, tid);
    int bx = blockIdx.x;
    if (bx < 504) {
        int i = (bx * 256 + tid) * 4;
        if (i < CONV_TOT) {
            const void* src; int off;
            if      (i < OFF_B1)   { src = embed; off = i; }
            else if (i < OFF_B2)   { src = b1;    off = i - OFF_B1; }
            else if (i < OFF_WOUT) { src = b2;    off = i - OFF_B2; }
            else if (i < OFF_BOUT) { src = Wout;  off = i - OFF_WOUT; }
            else                   { src = bout;  off = i - OFF_BOUT; }
            if (i + 3 < CONV_TOT) {
                ushort4 o;
                if (fb) {
                    o = *(const ushort4*)((const ushort_t*)src + off);
                } else {
                    float4 v = *(const float4*)((const float*)src + off);
                    o.x = f2b(v.x); o.y = f2b(v.y); o.z = f2b(v.z); o.w = f2b(v.w);
                }
                *(ushort4*)(conv + i) = o;
            } else {
                for (int k = 0; i + k < CONV_TOT; k++)
                    conv[i + k] = ld_bf16(src, off + k, fb);
            }
        }
    } else {
        __shared__ ushort_t t[32][33];
        int bi = bx - 504;
        const void* W = bi < 256 ? W1 : W2;
        ushort_t* WT = bi < 256 ? WT1 : WT2;
        int ti = bi & 255;
        int k0 = (ti & 15) * 32, n0 = (ti >> 4) * 32;
        int tx = tid & 31, ty = tid >> 5;
        #pragma unroll
        for (int i = ty; i < 32; i += 8)
            t[i][tx] = ld_bf16(W, (k0 + i) * HH + n0 + tx, fb);
        __syncthreads();
        #pragma unroll
        for (int i = ty; i < 32; i += 8)
            WT[(n0 + i) * HH + k0 + tx] = t[tx][i];
    }
}

// -------------------------------------------------------------- MLP layer
// Wave computes a 16x16 MFMA tile; grid (16,32)=512 blocks (2/CU).
__global__ __launch_bounds__(256) void mlp_layer(
    const ushort_t* __restrict__ A, const ushort_t* __restrict__ WT,
    const ushort_t* __restrict__ bias, ushort_t* __restrict__ H, int Mclamp)
{
    int tid = threadIdx.x;
    int lane = tid & 63;
    int wave = tid >> 6;
    int m_base = blockIdx.x * 64 + wave * 16;
    int n_base = blockIdx.y * 16;
    int lrow = lane & 15;
    int q = lane >> 4;
    int rowA = m_base + lrow; if (rowA > Mclamp) rowA = Mclamp;

    const short8* Ap = (const short8*)(A + (size_t)rowA * HH) + q;
    const short8* Bp = (const short8*)(WT + (size_t)(n_base + lrow) * HH) + q;

    f32x4 acc = {0.f, 0.f, 0.f, 0.f};
    #pragma unroll 8
    for (int kk = 0; kk < 16; kk++) {
        short8 a = Ap[kk * 4];
        short8 b = Bp[kk * 4];
        acc = __builtin_amdgcn_mfma_f32_16x16x32_bf16(a, b, acc, 0, 0, 0);
    }

    int orow = m_base + q * 4;                 // C/D: col=lane&15, row=q*4+reg
    int n = n_base + lrow;
    float bb = b2f(bias[n]);
    #pragma unroll
    for (int r = 0; r < 4; r++) {
        float v = acc[r] + bb;
        H[(size_t)(orow + r) * HH + n] = f2b(fmaxf(v, 0.f));
    }
}

// ---------------------------------------------------------------- params
__global__ __launch_bounds__(256) void params_kernel(
    const ushort_t* __restrict__ h2, const ushort_t* __restrict__ conv,
    float* __restrict__ table)
{
    int wid = blockIdx.x * 4 + (threadIdx.x >> 6);
    int lane = threadIdx.x & 63;
    if (wid >= SS * PP) return;
    int row = wid / PP, p = wid - row * PP;
    const ushort_t* Wout = conv + OFF_WOUT;
    const ushort_t* bout = conv + OFF_BOUT;
    const short8* hr = (const short8*)(h2 + (size_t)row * HH);
    short8 h = hr[lane];
    float acc = 0.f;
    #pragma unroll
    for (int j = 0; j < 8; j++) {
        int k = lane * 8 + j;
        acc += b2f((ushort_t)h[j]) * b2f(Wout[k * PP + p]);
    }
    #pragma unroll
    for (int m = 32; m; m >>= 1) acc += __shfl_xor(acc, m);
    if (lane == 0) {
        float x = acc + b2f(bout[p]);
        float sg = 1.f / (1.f + expf(-x));
        sg = fminf(fmaxf(sg, 1e-6f), 1.f - 1e-6f);
        table[(size_t)row * 8 + p] = sg;
    }
}

// ---------------------------------------------------------------- scan_a
// 512 blocks x 256, 128 rows/block. y staged coalesced -> LDS nibbles; then
// waves 0-1 chain 128 rows with FULL 64-lane utilization (200 exact steps,
// latent-only), writing 8 checkpoints + 8 masks per row, planar-coalesced.
__global__ __launch_bounds__(256) void scan_a(
    const int* __restrict__ X, const int* __restrict__ y,
    const float* __restrict__ table,
    float* __restrict__ cpA, uint* __restrict__ maskA)
{
    __shared__ uchar ybit[128 * 50];           // 6400 B
    int tid = threadIdx.x;
    int rbase = blockIdx.x * 128;

    for (int idx = tid; idx < 6400; idx += 256) {
        int r = idx / 50, k = idx - r * 50;
        int4 v = *(const int4*)(y + (size_t)(rbase + r) * TT + k * 4);
        ybit[r * 50 + k] = (uchar)((uint)(v.x == 1) | ((uint)(v.y == 1) << 1) |
                                   ((uint)(v.z == 1) << 2) | ((uint)(v.w == 1) << 3));
    }
    __syncthreads();

    if (tid < 128) {
        int rg = rbase + tid;
        int xi = X[rg]; xi = xi < 0 ? 0 : (xi >= SS ? SS - 1 : xi);
        float l      = table[xi * 8 + 0];
        float g      = table[xi * 8 + 2];
        float s      = table[xi * 8 + 3];
        float latent = table[xi * 8 + 4];
        float oms = 1.f - s, omg = 1.f - g, oml = 1.f - l;
        float A1 = 1.f - s - g, A0 = s + g - 1.f;
        float cp[8]; uint mk[8];
        #pragma unroll
        for (int w = 0; w < 8; w++) {
            cp[w] = latent;
            uint m = 0;
            // 25 steps: nibble-aligned walk over absolute t = w*25 + i
            #pragma unroll
            for (int i = 0; i < 25; i++) {
                int t_ = w * 25 + i;
                uint bit = (ybit[tid * 50 + (t_ >> 2)] >> (t_ & 3)) & 1u;
                m |= bit << i;
                latent = bkt_step(latent, bit, oms, omg, A1, A0, g, s, oml, l);
            }
            mk[w] = m;
        }
        #pragma unroll
        for (int w = 0; w < 8; w++) {
            cpA[(size_t)w * BB_ + rg]   = cp[w];
            maskA[(size_t)w * BB_ + rg] = mk[w];
        }
    }
}

// ---------------------------------------------------------------- scan_b
// 2048 blocks x 256, 32 rows/block, 8 threads/row. Resume from checkpoint,
// 25-step bit-exact re-emission of latents into a 32x200 LDS tile (2-way
// bank alias = free), one barrier, sweep computes corrects = fma(lat,A1,g)
// and streams both outputs as contiguous plain uint4 stores.
__global__ __launch_bounds__(256) void scan_b(
    const int* __restrict__ X, const float* __restrict__ table,
    const float* __restrict__ cpA, const uint* __restrict__ maskA,
    const uint* __restrict__ embed_raw, void* __restrict__ out)
{
    __shared__ __align__(16) float stg[32 * 200];      // 25600 B
    __shared__ float pA1[32], pG[32];
    int tid = threadIdx.x;
    int rbase = blockIdx.x * 32;
    int fb = detect_bf16(embed_raw, tid);

    int r = tid >> 3, j = tid & 7;
    int rg = rbase + r;
    int xi = X[rg]; xi = xi < 0 ? 0 : (xi >= SS ? SS - 1 : xi);
    float l  = table[xi * 8 + 0];
    float p1 = table[xi * 8 + 1];
    float g  = table[xi * 8 + 2];
    float s  = table[xi * 8 + 3];
    float L0 = table[xi * 8 + 4];

    if (j == 0) { pA1[r] = 1.f - s - g; pG[r] = g; }

    if (j < 5) {
        float pv = j == 0 ? l : j == 1 ? p1 : j == 2 ? g : j == 3 ? s : L0;
        size_t po = 2ull * BB_ * TT + (size_t)rg * 5 + j;
        if (fb) ((ushort_t*)out)[po] = f2b(pv);
        else    ((float*)out)[po] = pv;
    }

    float latent = cpA[(size_t)j * BB_ + rg];
    uint  u      = maskA[(size_t)j * BB_ + rg];
    float oms = 1.f - s, omg = 1.f - g, oml = 1.f - l;
    float A1 = 1.f - s - g, A0 = s + g - 1.f;

    int sbase = r * 200 + j * 25;              // 2-way bank alias = free
    #pragma unroll
    for (int i = 0; i < 25; i++) {
        stg[sbase + i] = latent;
        latent = bkt_step(latent, (u >> i) & 1u,
                          oms, omg, A1, A0, g, s, oml, l);
    }
    __syncthreads();

    const f32x4* src = (const f32x4*)stg;
    if (!fb) {
        f32x4* dc = (f32x4*)((float*)out + (size_t)rbase * TT);
        f32x4* dl = (f32x4*)((float*)out + (size_t)BB_ * TT + (size_t)rbase * TT);
        for (int idx = tid; idx < 1600; idx += 256) {
            int rr = idx / 50;
            f32x4 v = src[idx];
            float a1 = pA1[rr], gg = pG[rr];
            f32x4 c;
            c[0] = fmaf(v[0], a1, gg); c[1] = fmaf(v[1], a1, gg);
            c[2] = fmaf(v[2], a1, gg); c[3] = fmaf(v[3], a1, gg);
            dl[idx] = v;
            dc[idx] = c;
        }
    } else {
        uint2v* dc = (uint2v*)((ushort_t*)out + (size_t)rbase * TT);
        uint2v* dl = (uint2v*)((ushort_t*)out + (size_t)BB_ * TT + (size_t)rbase * TT);
        for (int idx = tid; idx < 1600; idx += 256) {
            int rr = idx / 50;
            f32x4 v = src[idx];
            float a1 = pA1[rr], gg = pG[rr];
            uint2v lv, cv;
            lv[0] = (uint)f2b(v[0]) | ((uint)f2b(v[1]) << 16);
            lv[1] = (uint)f2b(v[2]) | ((uint)f2b(v[3]) << 16);
            cv[0] = (uint)f2b(fmaf(v[0], a1, gg)) | ((uint)f2b(fmaf(v[1], a1, gg)) << 16);
            cv[1] = (uint)f2b(fmaf(v[2], a1, gg)) | ((uint)f2b(fmaf(v[3], a1, gg)) << 16);
            dl[idx] = lv;
            dc[idx] = cv;
        }
    }
}

// ---------------------------------------------------------------- launch
extern "C" void kernel_launch(void* const* d_in, const int* in_sizes, int n_in,
                              void* d_out, int out_size, void* d_ws, size_t ws_size,
                              hipStream_t stream) {
    const int* X = (const int*)d_in[0];
    const int* y = (const int*)d_in[1];

    char* ws = (char*)d_ws;
    ushort_t* conv  = (ushort_t*)(ws);                 // ~1.03 MB
    ushort_t* WT1   = (ushort_t*)(ws + 1048576);       // 512 KB
    ushort_t* WT2   = (ushort_t*)(ws + 1572864);       // 512 KB
    ushort_t* h1    = (ushort_t*)(ws + 2097152);       // 1 MB
    ushort_t* h2    = (ushort_t*)(ws + 3145728);       // 1 MB
    float*    table = (float*)(ws + 4194304);          // 32 KB
    float*    cpA   = (float*)(ws + 4227072);          // 2 MB
    uint*     maskA = (uint*)(ws + 6324224);           // 2 MB

    prep_kernel<<<dim3(1016, 1, 1), 256, 0, stream>>>(
        d_in[2], d_in[3], d_in[4], d_in[5], d_in[6], d_in[7], d_in[8],
        conv, WT1, WT2);
    mlp_layer<<<dim3(16, 32, 1), 256, 0, stream>>>(
        conv + OFF_EMB, WT1, conv + OFF_B1, h1, SS - 1);
    mlp_layer<<<dim3(16, 32, 1), 256, 0, stream>>>(
        h1, WT2, conv + OFF_B2, h2, 1023);
    params_kernel<<<dim3(1250, 1, 1), 256, 0, stream>>>(h2, conv, table);
    scan_a<<<dim3(512, 1, 1), 256, 0, stream>>>(X, y, table, cpA, maskA);
    scan_b<<<dim3(2048, 1, 1), 256, 0, stream>>>(
        X, table, cpA, maskA, (const uint*)d_in[2], (void*)d_out);
}

// Round 5
// 202.808 us; speedup vs baseline: 1.0340x; 1.0138x over previous
//
#include <hip/hip_runtime.h>

// MLP depends only on X[b] (1000 distinct values) -> params table, gathered
// by the scan. R17: move y->bitmask compression INTO prep as extra blocks
// (wide multi-role grid, 1016+1024 blocks — keeps width, unlike R13's
// narrow fusion). ypack blocks read the 52.4MB y and emit the planar
// 8x25-bit masks scan_a/scan_b already consume (2MB). scan_a loses ALL y
// staging (reads 2MB masks, likely L2-resident) and becomes a pure chain
// kernel (no LDS, no barrier). Bit-exact: same bit predicate, same t-order,
// same chain math.
// Session evidence log:
//   R13 fuse mlp chain narrow (63 blocks): +27.6us — narrow grid kills it.
//   R14 scan_b 4->12 blocks/CU: +2.3us — not occupancy-limited.
//   R15 single-pass scan: +6.3us — a/b replay split is free; 512-wide
//        chain blocks hide the serial chain best.
//   R16 revert = 205.6 vs 203.4-203.6 — noise band ±2us.
// Kept lessons: R5 strided stores = 4.85x write amp -> LDS tile +
// contiguous stores; R7 grid.sync ~60us/barrier; R8 per-load dtype branch =
// latency death.

typedef unsigned int uint;
typedef unsigned char uchar;
typedef unsigned short ushort_t;
typedef __attribute__((ext_vector_type(8))) short short8;
typedef __attribute__((ext_vector_type(4))) float f32x4;
typedef __attribute__((ext_vector_type(2))) uint uint2v;

#define SS 1000
#define HH 512
#define TT 200
#define BB_ 65536
#define PP 5

#define OFF_EMB   0
#define OFF_B1    512000
#define OFF_B2    512512
#define OFF_WOUT  513024
#define OFF_BOUT  515584
#define CONV_TOT  515589

__device__ __forceinline__ float b2f(ushort_t u) {
    return __uint_as_float(((uint)u) << 16);
}
__device__ __forceinline__ ushort_t f2b(float f) {
    uint u = __float_as_uint(f);
    uint r = u + 0x7FFFu + ((u >> 16) & 1u);   // RNE
    return (ushort_t)(r >> 16);
}
// Per-wave dtype detect (R2-R16: dataset is f32; keep both paths).
__device__ __forceinline__ int detect_bf16(const uint* __restrict__ embed_raw,
                                           int tid) {
    uint w = embed_raw[tid & 63];
    uint e = (w >> 7) & 0xFFu;
    bool pl = (e >= 117u && e <= 130u);
    return __popcll(__ballot(pl)) >= 32 ? 1 : 0;
}
__device__ __forceinline__ ushort_t ld_bf16(const void* src, int idx, int fb) {
    return fb ? ((const ushort_t*)src)[idx] : f2b(((const float*)src)[idx]);
}

// The one true scan step (same fp ops/order in scan_a and scan_b so
// checkpoint-resumed trajectories are bit-exact).
__device__ __forceinline__ float bkt_step(float latent, bool yt,
                                          float oms, float omg, float A1,
                                          float A0, float g, float s,
                                          float oml, float l) {
    float num1    = latent * oms;
    float correct = fmaf(latent, A1, g);
    float lats    = latent * s;
    float num = yt ? num1 : lats;
    float den = yt ? correct : fmaf(latent, A0, omg);
    float kt  = num * __builtin_amdgcn_rcpf(den);
    float nxt = fmaf(kt, oml, l);
    return fminf(fmaxf(nxt, 1e-6f), 1.f - 1e-6f);
}

// ------------------------------------------------------------------- prep
// [0,504): vectorized conv copy. [504,1016): 32x32 transpose tiles W1/W2.
// [1016,2040): ypack — 64 rows/block, y int4 -> LDS nibbles -> 8 planar
// 25-bit masks/row into maskA (identical bit values/order to old scan_a).
__global__ __launch_bounds__(256) void prep_kernel(
    const void* __restrict__ embed, const void* __restrict__ W1,
    const void* __restrict__ b1,    const void* __restrict__ W2,
    const void* __restrict__ b2,    const void* __restrict__ Wout,
    const void* __restrict__ bout,  const int* __restrict__ y,
    ushort_t* __restrict__ conv, ushort_t* __restrict__ WT1,
    ushort_t* __restrict__ WT2,  uint* __restrict__ maskA)
{
    int tid = threadIdx.x;
    int bx = blockIdx.x;
    if (bx < 504) {
        int fb = detect_bf16((const uint*)embed, tid);
        int i = (bx * 256 + tid) * 4;
        if (i < CONV_TOT) {
            const void* src; int off;
            if      (i < OFF_B1)   { src = embed; off = i; }
            else if (i < OFF_B2)   { src = b1;    off = i - OFF_B1; }
            else if (i < OFF_WOUT) { src = b2;    off = i - OFF_B2; }
            else if (i < OFF_BOUT) { src = Wout;  off = i - OFF_WOUT; }
            else                   { src = bout;  off = i - OFF_BOUT; }
            if (i + 3 < CONV_TOT) {
                ushort4 o;
                if (fb) {
                    o = *(const ushort4*)((const ushort_t*)src + off);
                } else {
                    float4 v = *(const float4*)((const float*)src + off);
                    o.x = f2b(v.x); o.y = f2b(v.y); o.z = f2b(v.z); o.w = f2b(v.w);
                }
                *(ushort4*)(conv + i) = o;
            } else {
                for (int k = 0; i + k < CONV_TOT; k++)
                    conv[i + k] = ld_bf16(src, off + k, fb);
            }
        }
    } else if (bx < 1016) {
        int fb = detect_bf16((const uint*)embed, tid);
        __shared__ ushort_t t[32][33];
        int bi = bx - 504;
        const void* W = bi < 256 ? W1 : W2;
        ushort_t* WT = bi < 256 ? WT1 : WT2;
        int ti = bi & 255;
        int k0 = (ti & 15) * 32, n0 = (ti >> 4) * 32;
        int tx = tid & 31, ty = tid >> 5;
        #pragma unroll
        for (int i = ty; i < 32; i += 8)
            t[i][tx] = ld_bf16(W, (k0 + i) * HH + n0 + tx, fb);
        __syncthreads();
        #pragma unroll
        for (int i = ty; i < 32; i += 8)
            WT[(n0 + i) * HH + k0 + tx] = t[tx][i];
    } else {
        __shared__ uchar yb[64 * 50];          // 3200 B
        int rbase = (bx - 1016) * 64;
        for (int idx = tid; idx < 3200; idx += 256) {
            int r = idx / 50, k = idx - r * 50;
            int4 v = *(const int4*)(y + (size_t)(rbase + r) * TT + k * 4);
            yb[r * 50 + k] = (uchar)((uint)(v.x == 1) | ((uint)(v.y == 1) << 1) |
                                     ((uint)(v.z == 1) << 2) | ((uint)(v.w == 1) << 3));
        }
        __syncthreads();
        #pragma unroll
        for (int it = 0; it < 2; it++) {
            int task = tid + it * 256;         // 512 tasks = 64 rows x 8 w
            int r = task & 63, w = task >> 6;  // consecutive tid -> consecutive r
            uint m = 0;
            #pragma unroll
            for (int i = 0; i < 25; i++) {
                int t_ = w * 25 + i;
                m |= (uint)((yb[r * 50 + (t_ >> 2)] >> (t_ & 3)) & 1u) << i;
            }
            maskA[(size_t)w * BB_ + rbase + r] = m;
        }
    }
}

// -------------------------------------------------------------- MLP layer
// Wave computes a 16x16 MFMA tile; grid (16,32)=512 blocks (2/CU).
__global__ __launch_bounds__(256) void mlp_layer(
    const ushort_t* __restrict__ A, const ushort_t* __restrict__ WT,
    const ushort_t* __restrict__ bias, ushort_t* __restrict__ H, int Mclamp)
{
    int tid = threadIdx.x;
    int lane = tid & 63;
    int wave = tid >> 6;
    int m_base = blockIdx.x * 64 + wave * 16;
    int n_base = blockIdx.y * 16;
    int lrow = lane & 15;
    int q = lane >> 4;
    int rowA = m_base + lrow; if (rowA > Mclamp) rowA = Mclamp;

    const short8* Ap = (const short8*)(A + (size_t)rowA * HH) + q;
    const short8* Bp = (const short8*)(WT + (size_t)(n_base + lrow) * HH) + q;

    f32x4 acc = {0.f, 0.f, 0.f, 0.f};
    #pragma unroll 8
    for (int kk = 0; kk < 16; kk++) {
        short8 a = Ap[kk * 4];
        short8 b = Bp[kk * 4];
        acc = __builtin_amdgcn_mfma_f32_16x16x32_bf16(a, b, acc, 0, 0, 0);
    }

    int orow = m_base + q * 4;                 // C/D: col=lane&15, row=q*4+reg
    int n = n_base + lrow;
    float bb = b2f(bias[n]);
    #pragma unroll
    for (int r = 0; r < 4; r++) {
        float v = acc[r] + bb;
        H[(size_t)(orow + r) * HH + n] = f2b(fmaxf(v, 0.f));
    }
}

// ---------------------------------------------------------------- params
__global__ __launch_bounds__(256) void params_kernel(
    const ushort_t* __restrict__ h2, const ushort_t* __restrict__ conv,
    float* __restrict__ table)
{
    int wid = blockIdx.x * 4 + (threadIdx.x >> 6);
    int lane = threadIdx.x & 63;
    if (wid >= SS * PP) return;
    int row = wid / PP, p = wid - row * PP;
    const ushort_t* Wout = conv + OFF_WOUT;
    const ushort_t* bout = conv + OFF_BOUT;
    const short8* hr = (const short8*)(h2 + (size_t)row * HH);
    short8 h = hr[lane];
    float acc = 0.f;
    #pragma unroll
    for (int j = 0; j < 8; j++) {
        int k = lane * 8 + j;
        acc += b2f((ushort_t)h[j]) * b2f(Wout[k * PP + p]);
    }
    #pragma unroll
    for (int m = 32; m; m >>= 1) acc += __shfl_xor(acc, m);
    if (lane == 0) {
        float x = acc + b2f(bout[p]);
        float sg = 1.f / (1.f + expf(-x));
        sg = fminf(fmaxf(sg, 1e-6f), 1.f - 1e-6f);
        table[(size_t)row * 8 + p] = sg;
    }
}

// ---------------------------------------------------------------- scan_a
// R17: pure chain kernel. 512 blocks x 128, lane=row. Masks pre-packed by
// prep's ypack (2MB planar, likely L2-resident) — no y read, no LDS, no
// barrier. Chain order identical to R12 -> bit-exact checkpoints.
__global__ __launch_bounds__(128) void scan_a(
    const int* __restrict__ X, const float* __restrict__ table,
    const uint* __restrict__ maskA, float* __restrict__ cpA)
{
    int tid = threadIdx.x;
    int rg = blockIdx.x * 128 + tid;
    int xi = X[rg]; xi = xi < 0 ? 0 : (xi >= SS ? SS - 1 : xi);
    float l      = table[xi * 8 + 0];
    float g      = table[xi * 8 + 2];
    float s      = table[xi * 8 + 3];
    float latent = table[xi * 8 + 4];
    float oms = 1.f - s, omg = 1.f - g, oml = 1.f - l;
    float A1 = 1.f - s - g, A0 = s + g - 1.f;

    uint mk[8];
    #pragma unroll
    for (int w = 0; w < 8; w++) mk[w] = maskA[(size_t)w * BB_ + rg];

    float cp[8];
    #pragma unroll
    for (int w = 0; w < 8; w++) {
        cp[w] = latent;
        #pragma unroll
        for (int i = 0; i < 25; i++)
            latent = bkt_step(latent, (mk[w] >> i) & 1u,
                              oms, omg, A1, A0, g, s, oml, l);
    }
    #pragma unroll
    for (int w = 0; w < 8; w++)
        cpA[(size_t)w * BB_ + rg] = cp[w];
}

// ---------------------------------------------------------------- scan_b
// 2048 blocks x 256, 32 rows/block, 8 threads/row. Resume from checkpoint,
// 25-step bit-exact re-emission of latents into a 32x200 LDS tile (2-way
// bank alias = free), one barrier, sweep computes corrects = fma(lat,A1,g)
// and streams both outputs as contiguous plain uint4 stores.
__global__ __launch_bounds__(256) void scan_b(
    const int* __restrict__ X, const float* __restrict__ table,
    const float* __restrict__ cpA, const uint* __restrict__ maskA,
    const uint* __restrict__ embed_raw, void* __restrict__ out)
{
    __shared__ __align__(16) float stg[32 * 200];      // 25600 B
    __shared__ float pA1[32], pG[32];
    int tid = threadIdx.x;
    int rbase = blockIdx.x * 32;
    int fb = detect_bf16(embed_raw, tid);

    int r = tid >> 3, j = tid & 7;
    int rg = rbase + r;
    int xi = X[rg]; xi = xi < 0 ? 0 : (xi >= SS ? SS - 1 : xi);
    float l  = table[xi * 8 + 0];
    float p1 = table[xi * 8 + 1];
    float g  = table[xi * 8 + 2];
    float s  = table[xi * 8 + 3];
    float L0 = table[xi * 8 + 4];

    if (j == 0) { pA1[r] = 1.f - s - g; pG[r] = g; }

    if (j < 5) {
        float pv = j == 0 ? l : j == 1 ? p1 : j == 2 ? g : j == 3 ? s : L0;
        size_t po = 2ull * BB_ * TT + (size_t)rg * 5 + j;
        if (fb) ((ushort_t*)out)[po] = f2b(pv);
        else    ((float*)out)[po] = pv;
    }

    float latent = cpA[(size_t)j * BB_ + rg];
    uint  u      = maskA[(size_t)j * BB_ + rg];
    float oms = 1.f - s, omg = 1.f - g, oml = 1.f - l;
    float A1 = 1.f - s - g, A0 = s + g - 1.f;

    int sbase = r * 200 + j * 25;              // 2-way bank alias = free
    #pragma unroll
    for (int i = 0; i < 25; i++) {
        stg[sbase + i] = latent;
        latent = bkt_step(latent, (u >> i) & 1u,
                          oms, omg, A1, A0, g, s, oml, l);
    }
    __syncthreads();

    const f32x4* src = (const f32x4*)stg;
    if (!fb) {
        f32x4* dc = (f32x4*)((float*)out + (size_t)rbase * TT);
        f32x4* dl = (f32x4*)((float*)out + (size_t)BB_ * TT + (size_t)rbase * TT);
        for (int idx = tid; idx < 1600; idx += 256) {
            int rr = idx / 50;
            f32x4 v = src[idx];
            float a1 = pA1[rr], gg = pG[rr];
            f32x4 c;
            c[0] = fmaf(v[0], a1, gg); c[1] = fmaf(v[1], a1, gg);
            c[2] = fmaf(v[2], a1, gg); c[3] = fmaf(v[3], a1, gg);
            dl[idx] = v;
            dc[idx] = c;
        }
    } else {
        uint2v* dc = (uint2v*)((ushort_t*)out + (size_t)rbase * TT);
        uint2v* dl = (uint2v*)((ushort_t*)out + (size_t)BB_ * TT + (size_t)rbase * TT);
        for (int idx = tid; idx < 1600; idx += 256) {
            int rr = idx / 50;
            f32x4 v = src[idx];
            float a1 = pA1[rr], gg = pG[rr];
            uint2v lv, cv;
            lv[0] = (uint)f2b(v[0]) | ((uint)f2b(v[1]) << 16);
            lv[1] = (uint)f2b(v[2]) | ((uint)f2b(v[3]) << 16);
            cv[0] = (uint)f2b(fmaf(v[0], a1, gg)) | ((uint)f2b(fmaf(v[1], a1, gg)) << 16);
            cv[1] = (uint)f2b(fmaf(v[2], a1, gg)) | ((uint)f2b(fmaf(v[3], a1, gg)) << 16);
            dl[idx] = lv;
            dc[idx] = cv;
        }
    }
}

// ---------------------------------------------------------------- launch
extern "C" void kernel_launch(void* const* d_in, const int* in_sizes, int n_in,
                              void* d_out, int out_size, void* d_ws, size_t ws_size,
                              hipStream_t stream) {
    const int* X = (const int*)d_in[0];
    const int* y = (const int*)d_in[1];

    char* ws = (char*)d_ws;
    ushort_t* conv  = (ushort_t*)(ws);                 // ~1.03 MB
    ushort_t* WT1   = (ushort_t*)(ws + 1048576);       // 512 KB
    ushort_t* WT2   = (ushort_t*)(ws + 1572864);       // 512 KB
    ushort_t* h1    = (ushort_t*)(ws + 2097152);       // 1 MB
    ushort_t* h2    = (ushort_t*)(ws + 3145728);       // 1 MB
    float*    table = (float*)(ws + 4194304);          // 32 KB
    float*    cpA   = (float*)(ws + 4227072);          // 2 MB
    uint*     maskA = (uint*)(ws + 6324224);           // 2 MB

    prep_kernel<<<dim3(2040, 1, 1), 256, 0, stream>>>(
        d_in[2], d_in[3], d_in[4], d_in[5], d_in[6], d_in[7], d_in[8], y,
        conv, WT1, WT2, maskA);
    mlp_layer<<<dim3(16, 32, 1), 256, 0, stream>>>(
        conv + OFF_EMB, WT1, conv + OFF_B1, h1, SS - 1);
    mlp_layer<<<dim3(16, 32, 1), 256, 0, stream>>>(
        h1, WT2, conv + OFF_B2, h2, 1023);
    params_kernel<<<dim3(1250, 1, 1), 256, 0, stream>>>(h2, conv, table);
    scan_a<<<dim3(512, 1, 1), 128, 0, stream>>>(X, table, maskA, cpA);
    scan_b<<<dim3(2048, 1, 1), 256, 0, stream>>>(
        X, table, cpA, maskA, (const uint*)d_in[2], (void*)d_out);
}